// Round 8
// baseline (84.685 us; speedup 1.0000x reference)
//
#include <hip/hip_runtime.h>
#include <stdint.h>

// GAT: N=4096, F_in=512, H=8, F_out=64.
// exp(lrelu(s_i+d_j)) = max(e^{s_i} e^{d_j}, e^{0.2 s_i} e^{0.2 d_j})  (exact)
// Round 8: occupancy fix — 32-row blocks x 8 waves (2 rt x 4 jseg), PH=1,
// grid 1024 = 4 blocks/CU = 32 waves/CU. Shift-spread mask trick
// (t=bb|(bb<<15); (t<<(14-2k))&0x40004000 = fp16 2.0 halfword masks).
// Static double-buffer pointers via manually 2x-unrolled phase loop.

#define NN 4096
#define FIN 512
#define NH 8
#define FO 64

typedef _Float16 f16x8 __attribute__((ext_vector_type(8)));
typedef _Float16 f16x2 __attribute__((ext_vector_type(2)));
typedef __attribute__((ext_vector_type(4))) float f32x4;

union H8 { f16x8 v; f16x2 p[4]; unsigned u[4]; };
union U2 { unsigned u; f16x2 v; };

#define GLOAD_LDS16(g, l)                                                          \
  __builtin_amdgcn_global_load_lds((__attribute__((address_space(1))) const void*)(g), \
                                   (__attribute__((address_space(3))) void*)(l), 16, 0, 0)
#define GLOAD_LDS4(g, l)                                                           \
  __builtin_amdgcn_global_load_lds((__attribute__((address_space(1))) const void*)(g), \
                                   (__attribute__((address_space(3))) void*)(l), 4, 0, 0)

__device__ __forceinline__ unsigned short f2h(float f) {
  _Float16 h = (_Float16)f;               // RNE
  return __builtin_bit_cast(unsigned short, h);
}

// ---------------- prep: adj->bitsT, X->fp16, W->WbT(fp16), wa = W^T a ----------------
__global__ __launch_bounds__(256) void prep_kernel(
    const float* __restrict__ X, const int* __restrict__ adj, const float* __restrict__ W,
    const float* __restrict__ a,
    unsigned short* __restrict__ Xh, unsigned short* __restrict__ WbT,
    unsigned* __restrict__ adjbitsT, unsigned short* __restrict__ WAh) {
  int bid = blockIdx.x, tid = threadIdx.x;
  if (bid < 2048) {                       // adj -> bit words, transposed [jt][r]
    int item = bid * 256 + tid;           // item = jt*4096 + r
    int jt = item >> 12, r = item & 4095;
    const int* p = adj + (size_t)r * NN + jt * 32;
    unsigned bits = 0;
#pragma unroll
    for (int b = 0; b < 32; b += 4) {
      int4 v = *(const int4*)(p + b);
      bits |= (unsigned)(v.x & 1) << b;
      bits |= (unsigned)(v.y & 1) << (b + 1);
      bits |= (unsigned)(v.z & 1) << (b + 2);
      bits |= (unsigned)(v.w & 1) << (b + 3);
    }
    adjbitsT[item] = bits;
  } else if (bid < 4096) {                // X -> fp16
    int item = (bid - 2048) * 256 + tid;
    float4 v = ((const float4*)X)[item];
    ushort4 o;
    o.x = f2h(v.x); o.y = f2h(v.y); o.z = f2h(v.z); o.w = f2h(v.w);
    ((ushort4*)Xh)[item] = o;
  } else if (bid < 5120) {                // W[h][k][o] -> WbT[h][o][k] fp16
    int item = (bid - 4096) * 256 + tid;
    int h = item >> 15, rem = item & 32767, o = rem >> 9, k = rem & 511;
    WbT[item] = f2h(W[h * (FIN * FO) + k * FO + o]);
  } else {                                // wa[t][k] = sum_o W[h][k][o] * a[h][which*64+o]
    int item = (bid - 5120) * 256 + tid;  // 8192 items: t = h*2+which, k
    int h = item >> 10, which = (item >> 9) & 1, k = item & 511;
    const float4* wp = (const float4*)(W + ((size_t)h * FIN + k) * FO);
    const float4* ap = (const float4*)(a + h * 128 + which * 64);
    float s = 0.f;
#pragma unroll
    for (int o4 = 0; o4 < 16; ++o4) {
      float4 w4 = wp[o4], a4 = ap[o4];
      s += w4.x * a4.x + w4.y * a4.y + w4.z * a4.z + w4.w * a4.w;
    }
    WAh[(h * 2 + which) * FIN + k] = f2h(s);
  }
}

// ---------------- proj (+sd): Wh fragments fp16, s,d -> AB / E1h,E2h tables ---------
// D layout (16x16x32): col = lane&15, row = (lane>>4)*4 + reg   [m89]
__global__ __launch_bounds__(256, 4) void proj_sd_kernel(
    const unsigned short* __restrict__ Xh, const unsigned short* __restrict__ WbT,
    const unsigned short* __restrict__ WAh,
    unsigned short* __restrict__ Whfrag, float2* __restrict__ ABf,
    unsigned short* __restrict__ E1h, unsigned short* __restrict__ E2h) {
  int lane = threadIdx.x & 63, wave = threadIdx.x >> 6;
  int row16 = lane & 15, grp = lane >> 4;
  if (blockIdx.y == 8) {                  // sd: [s,d]x8 = X @ WA  (16 cols, K=512)
    int i0 = (blockIdx.x * 4 + wave) * 16;
    f32x4 acc = {0, 0, 0, 0};
    const unsigned short* xb = Xh + (size_t)(i0 + row16) * FIN + grp * 8;
    const unsigned short* wb = WAh + row16 * FIN + grp * 8;
#pragma unroll
    for (int k0 = 0; k0 < FIN; k0 += 32)
      acc = __builtin_amdgcn_mfma_f32_16x16x32_f16(*(const f16x8*)(xb + k0),
                                                   *(const f16x8*)(wb + k0), acc, 0, 0, 0);
    int hh = row16 >> 1;
#pragma unroll
    for (int reg = 0; reg < 4; ++reg) {
      int rr = i0 + grp * 4 + reg;
      float v = acc[reg];
      if (row16 & 1) {                    // d -> col tables fp16
        E1h[hh * NN + rr] = f2h(__expf(v));
        E2h[hh * NN + rr] = f2h(__expf(0.2f * v));
      } else {                            // s -> row tables f32
        ABf[hh * NN + rr] = make_float2(__expf(v), __expf(0.2f * v));
      }
    }
    return;
  }
  int h = blockIdx.y;
  int i0 = blockIdx.x * 64 + wave * 16;
  f32x4 acc[4] = {{0,0,0,0},{0,0,0,0},{0,0,0,0},{0,0,0,0}};
  const unsigned short* xb = Xh + (size_t)(i0 + row16) * FIN + grp * 8;
  const unsigned short* wb = WbT + h * (FO * FIN) + row16 * FIN + grp * 8;
#pragma unroll 4
  for (int k0 = 0; k0 < FIN; k0 += 32) {
    f16x8 af = *(const f16x8*)(xb + k0);
#pragma unroll
    for (int cb = 0; cb < 4; ++cb)
      acc[cb] = __builtin_amdgcn_mfma_f32_16x16x32_f16(
          af, *(const f16x8*)(wb + cb * 16 * FIN + k0), acc[cb], 0, 0, 0);
  }
  // Whfrag[h][jt][cb][l][e] = Wh[jt*32 + (l>>4)*8 + e][cb*16 + (l&15)]
  int jt = i0 >> 5;
  int kk0 = (i0 & 31) + grp * 4;
  int tl = (kk0 >> 3) * 16 + row16;
  int e0 = kk0 & 7;
#pragma unroll
  for (int cb = 0; cb < 4; ++cb) {
    ushort4 pk;
    pk.x = f2h(acc[cb][0]); pk.y = f2h(acc[cb][1]);
    pk.z = f2h(acc[cb][2]); pk.w = f2h(acc[cb][3]);
    *(ushort4*)(Whfrag + (((size_t)h * 128 + jt) * 4 + cb) * 512 + tl * 8 + e0) = pk;
  }
}

// ---------------- gat: 2-phase LDS pipeline, 2 rt x 4 jseg, 32 rows/block ----------
// SEG per (jseg,buf): [B 4096 | E1 64 | E2 64 | adj 128] = 4352 -> 4608; x8 = 36 KB
#define SEGB 4608
#define E_OFF 4096
#define A_OFF 4224

__global__ __launch_bounds__(512, 8) void gat_kernel(
    const unsigned* __restrict__ adjbitsT, const unsigned short* __restrict__ Whfrag,
    const float2* __restrict__ ABf, const unsigned short* __restrict__ E1h,
    const unsigned short* __restrict__ E2h, float* __restrict__ out) {
  __shared__ __align__(16) char lds[8 * SEGB];
  int h = blockIdx.y;
  int lane = threadIdx.x & 63, wave = threadIdx.x >> 6;
  int row16 = lane & 15, grp = lane >> 4;
  int rt = wave >> 2, jseg = wave & 3;
  int r0 = blockIdx.x * 32;
  int i0 = r0 + rt * 16;
  int r = i0 + row16;
  float2 ab = ABf[h * NN + r];
  _Float16 Ah1 = (_Float16)(0.5f * ab.x);   // pre-halved: mask supplies x2
  _Float16 Bh1 = (_Float16)(0.5f * ab.y);
  f16x2 Ah = {Ah1, Ah1}, Bh = {Bh1, Bh1};

  H8 ones;
#pragma unroll
  for (int k = 0; k < 4; ++k) ones.u[k] = 0x3C003C00u;   // fp16 1.0 pairs

  // per-jseg hoisted source pointers
  const unsigned short* wsrc =
      Whfrag + (size_t)h * 262144 + (size_t)jseg * 32 * 2048 + lane * 8;
  const unsigned short* esrc =
      ((lane & 4) ? E2h : E1h) + h * NN + jseg * 1024 + (lane & 3) * 8;
  const unsigned* asrc = adjbitsT + (size_t)(jseg * 32) * NN + r0 + lane;

  f32x4 a0 = {0,0,0,0}, a1 = {0,0,0,0}, a2 = {0,0,0,0}, ad = {0,0,0,0}, aden = {0,0,0,0};

  char* seg0 = lds + (jseg * 2 + 0) * SEGB;
  char* seg1 = lds + (jseg * 2 + 1) * SEGB;

  auto stage = [&](char* seg, int p) {     // stage tile (jseg*32+p) into seg
    if (rt == 0) {                         // B-frags: 4 KB
      const unsigned short* bs = wsrc + (size_t)p * 2048;
      GLOAD_LDS16(bs, seg);
      GLOAD_LDS16(bs + 512, seg + 1024);
      GLOAD_LDS16(bs + 1024, seg + 2048);
      GLOAD_LDS16(bs + 1536, seg + 3072);
    } else {                               // adj 128 B + E 128 B
      if (lane < 32) GLOAD_LDS4(asrc + (size_t)p * NN, seg + A_OFF);
      if (lane < 8)  GLOAD_LDS16(esrc + p * 32, seg + E_OFF);
    }
  };

  auto compute = [&](const char* seg) {
    unsigned bw = *(const unsigned*)(seg + A_OFF + (rt * 16 + row16) * 4);
    unsigned bb = (bw >> (grp * 8)) & 0xffu;
    unsigned t32 = bb | (bb << 15);        // bit h at {h, h+15}
    H8 e1, e2;
    e1.v = *(const f16x8*)(seg + E_OFF + grp * 16);
    e2.v = *(const f16x8*)(seg + E_OFF + 64 + grp * 16);
    const char* bp = seg + lane * 16;
    f16x8 b0 = *(const f16x8*)(bp);
    f16x8 b1 = *(const f16x8*)(bp + 1024);
    f16x8 b2 = *(const f16x8*)(bp + 2048);
    f16x8 b3 = *(const f16x8*)(bp + 3072);
    H8 af;
#pragma unroll
    for (int k = 0; k < 4; ++k) {
      U2 m;                                // halves: bit2k->pos14, bit2k+1->pos30 (fp16 2.0)
      m.u = (t32 << (14 - 2 * k)) & 0x40004000u;
      af.p[k] = __builtin_elementwise_max(Ah * e1.p[k], Bh * e2.p[k]) * m.v;
    }
    a0   = __builtin_amdgcn_mfma_f32_16x16x32_f16(af.v, b0, a0, 0, 0, 0);
    a1   = __builtin_amdgcn_mfma_f32_16x16x32_f16(af.v, b1, a1, 0, 0, 0);
    a2   = __builtin_amdgcn_mfma_f32_16x16x32_f16(af.v, b2, a2, 0, 0, 0);
    aden = __builtin_amdgcn_mfma_f32_16x16x32_f16(af.v, ones.v, aden, 0, 0, 0);
    ad   = __builtin_amdgcn_mfma_f32_16x16x32_f16(af.v, b3, ad, 0, 0, 0);
  };

  stage(seg0, 0);
  __syncthreads();
#pragma unroll 1
  for (int p2 = 0; p2 < 16; ++p2) {
    stage(seg1, 2 * p2 + 1);
    compute(seg0);
    __syncthreads();
    if (p2 < 15) stage(seg0, 2 * p2 + 2);
    compute(seg1);
    __syncthreads();
  }

  // ---- cross-jseg reduction (reuse LDS, 30720 B) + normalize + store ----
  float* red = (float*)lds;
  if (jseg != 0) {
    float* q = red + (((jseg - 1) * 2 + rt) * 64 + lane) * 20;
    *(f32x4*)(q +  0) = a0;
    *(f32x4*)(q +  4) = a1;
    *(f32x4*)(q +  8) = a2;
    *(f32x4*)(q + 12) = ad;
    *(f32x4*)(q + 16) = aden;
  }
  __syncthreads();
  if (jseg == 0) {
#pragma unroll
    for (int s = 0; s < 3; ++s) {
      const float* q = red + ((s * 2 + rt) * 64 + lane) * 20;
      a0   += *(const f32x4*)(q +  0);
      a1   += *(const f32x4*)(q +  4);
      a2   += *(const f32x4*)(q +  8);
      ad   += *(const f32x4*)(q + 12);
      aden += *(const f32x4*)(q + 16);
    }
#pragma unroll
    for (int reg = 0; reg < 4; ++reg) {
      float inv = 1.0f / aden[reg];
      int row = i0 + grp * 4 + reg;
      float* op = out + (size_t)row * (NH * FO) + h * FO + row16;
      op[0]  = a0[reg] * inv;
      op[16] = a1[reg] * inv;
      op[32] = a2[reg] * inv;
      op[48] = ad[reg] * inv;
    }
  }
}

extern "C" void kernel_launch(void* const* d_in, const int* in_sizes, int n_in,
                              void* d_out, int out_size, void* d_ws, size_t ws_size,
                              hipStream_t stream) {
  const float* X  = (const float*)d_in[0];
  const int* adj  = (const int*)d_in[1];
  const float* W  = (const float*)d_in[2];
  const float* a  = (const float*)d_in[3];
  float* out = (float*)d_out;
  char* ws = (char*)d_ws;

  unsigned short* Xh     = (unsigned short*)(ws + 0);          // 4 MB
  unsigned short* WbT    = (unsigned short*)(ws + 4194304);    // 512 KB
  unsigned* adjbitsT     = (unsigned*)(ws + 4718592);          // 2 MB
  unsigned short* Whfrag = (unsigned short*)(ws + 6815744);    // 4 MB
  unsigned short* WAh    = (unsigned short*)(ws + 11010048);   // 16 KB
  float2* ABf            = (float2*)(ws + 11026432);           // 256 KB
  unsigned short* E1h    = (unsigned short*)(ws + 11288576);   // 64 KB
  unsigned short* E2h    = (unsigned short*)(ws + 11354112);   // 64 KB (total ~11.4 MB)

  prep_kernel<<<5152, 256, 0, stream>>>(X, adj, W, a, Xh, WbT, adjbitsT, WAh);
  proj_sd_kernel<<<dim3(64, 9), 256, 0, stream>>>(Xh, WbT, WAh, Whfrag, ABf, E1h, E2h);
  gat_kernel<<<dim3(128, 8), 512, 0, stream>>>(adjbitsT, Whfrag, ABf, E1h, E2h, out);
}